// Round 8
// baseline (154.641 us; speedup 1.0000x reference)
//
#include <hip/hip_runtime.h>

#define BB 8
#define SS 2048
#define HH 768
#define DD 64
#define BK 64
#define NK (HH / BK)   // 12

typedef short bf16x8 __attribute__((ext_vector_type(8)));
typedef short bf16x4 __attribute__((ext_vector_type(4)));
typedef float f32x16 __attribute__((ext_vector_type(16)));
typedef float f32x4 __attribute__((ext_vector_type(4)));

#define EXPC 0.18033688011112042f   // log2(e)/8

static __device__ __forceinline__ short f2bf(float f) {
    union { float f; unsigned u; } v; v.f = f;
    unsigned u = v.u + 0x7fff + ((v.u >> 16) & 1);   // RNE
    return (short)(u >> 16);
}

// ---------------- Kernel 0: W transpose+convert -> wT bf16 [3][64][768] ----
__global__ __launch_bounds__(256) void w_convert(
    const float* __restrict__ Wq, const float* __restrict__ Wk,
    const float* __restrict__ Wv, short* __restrict__ wT)
{
    __shared__ float ws[64][65];
    const int jj   = blockIdx.x / 12;
    const int h0   = (blockIdx.x % 12) * 64;
    const int tid  = threadIdx.x;
    const float* Wsrc = (jj == 0) ? Wq : (jj == 1 ? Wk : Wv);

    {
        const int hl = tid >> 4;
        const int c4 = tid & 15;
        #pragma unroll
        for (int p = 0; p < 4; ++p) {
            const int h = hl + p * 16;
            float4 v = ((const float4*)(Wsrc + (long)(h0 + h) * DD))[c4];
            ws[h][c4 * 4 + 0] = v.x; ws[h][c4 * 4 + 1] = v.y;
            ws[h][c4 * 4 + 2] = v.z; ws[h][c4 * 4 + 3] = v.w;
        }
    }
    __syncthreads();

    const int d   = tid >> 2;
    const int seg = tid & 3;
    bf16x8 t0, t1;
    #pragma unroll
    for (int m = 0; m < 8; ++m) {
        t0[m] = f2bf(ws[seg * 16 + m][d]);
        t1[m] = f2bf(ws[seg * 16 + 8 + m][d]);
    }
    short* dst = wT + ((long)jj * 64 + d) * HH + h0 + seg * 16;
    *(bf16x8*)dst = t0;
    *(bf16x8*)(dst + 8) = t1;
}

// ---------------- Kernel 1: QKV projection via MFMA (unchanged) ----------
__global__ __launch_bounds__(384) void qkv_mfma(
    const float* __restrict__ x, const short* __restrict__ wT,
    const float* __restrict__ bq, const float* __restrict__ bk,
    const float* __restrict__ bv,
    short* __restrict__ qo, short* __restrict__ ko, short* __restrict__ vT)
{
    __shared__ short xs[2][32][68];

    const int tid  = threadIdx.x;
    const int w    = tid >> 6;
    const int lane = tid & 63;
    const int l31  = lane & 31;
    const int h    = lane >> 5;
    const long row0 = (long)blockIdx.x * 32;

    const int r0 = tid >> 4,        c0 = tid & 15;
    const int r1 = (tid + 384) >> 4, c1 = (tid + 384) & 15;
    const bool has1 = (tid + 384) < 512;

    f32x16 acc;
    #pragma unroll
    for (int i = 0; i < 16; ++i) acc[i] = 0.f;

    float4 st0, st1;
    st0 = ((const float4*)(x + (row0 + r0) * HH))[c0];
    if (has1) st1 = ((const float4*)(x + (row0 + r1) * HH))[c1];
    {
        bf16x4 b0; b0[0]=f2bf(st0.x); b0[1]=f2bf(st0.y); b0[2]=f2bf(st0.z); b0[3]=f2bf(st0.w);
        *(bf16x4*)&xs[0][r0][c0 * 4] = b0;
        if (has1) {
            bf16x4 b1; b1[0]=f2bf(st1.x); b1[1]=f2bf(st1.y); b1[2]=f2bf(st1.z); b1[3]=f2bf(st1.w);
            *(bf16x4*)&xs[0][r1][c1 * 4] = b1;
        }
    }
    __syncthreads();

    const int col = w * 32 + l31;
    const short* wcol = wT + (long)col * HH + h * 8;

    for (int it = 0; it < NK; ++it) {
        const int cur = it & 1;
        if (it < NK - 1) {
            st0 = ((const float4*)(x + (row0 + r0) * HH + (it + 1) * BK))[c0];
            if (has1) st1 = ((const float4*)(x + (row0 + r1) * HH + (it + 1) * BK))[c1];
        }
        #pragma unroll
        for (int kt = 0; kt < 4; ++kt) {
            bf16x8 af = *(const bf16x8*)&xs[cur][l31][kt * 16 + h * 8];
            bf16x8 bf = *(const bf16x8*)(wcol + it * BK + kt * 16);
            acc = __builtin_amdgcn_mfma_f32_32x32x16_bf16(af, bf, acc, 0, 0, 0);
        }
        if (it < NK - 1) {
            __syncthreads();
            bf16x4 b0; b0[0]=f2bf(st0.x); b0[1]=f2bf(st0.y); b0[2]=f2bf(st0.z); b0[3]=f2bf(st0.w);
            *(bf16x4*)&xs[cur ^ 1][r0][c0 * 4] = b0;
            if (has1) {
                bf16x4 b1; b1[0]=f2bf(st1.x); b1[1]=f2bf(st1.y); b1[2]=f2bf(st1.z); b1[3]=f2bf(st1.w);
                *(bf16x4*)&xs[cur ^ 1][r1][c1 * 4] = b1;
            }
            __syncthreads();
        }
    }

    short (*vs)[68] = xs[0];
    const int j = w >> 1;
    const int d = (w & 1) * 32 + l31;
    const float* bptr = (j == 0) ? bq : (j == 1 ? bk : bv);
    const float bias = bptr[d];

    __syncthreads();

    #pragma unroll
    for (int i = 0; i < 16; ++i) {
        const int r = (i & 3) + 8 * (i >> 2) + 4 * h;
        const short val = f2bf(acc[i] + bias);
        if (j == 0)      qo[(row0 + r) * DD + d] = val;
        else if (j == 1) ko[(row0 + r) * DD + d] = val;
        else             vs[r][d] = val;
    }
    __syncthreads();

    if (tid < 256) {
        const int b  = (int)(row0 >> 11);
        const int s0 = (int)(row0 & (SS - 1));
        const int dd  = tid >> 2;
        const int seg = tid & 3;
        bf16x8 t;
        #pragma unroll
        for (int m = 0; m < 8; ++m) t[m] = vs[seg * 8 + m][dd];
        *(bf16x8*)(vT + ((long)b * DD + dd) * SS + s0 + seg * 8) = t;
    }
}

// ---------------- Kernel 2: MFMA attention v5 (16 waves) ----------------
// 1024 threads (16 waves), 32 q-rows/block, wave w owns keys [w*128, +128).
// No-max softmax, bf16 P-packs in regs, V direct global, probs via per-wave
// LDS transpose. grid = B * (S/32) = 512.
__global__ __launch_bounds__(1024) void attn(
    const short* __restrict__ qb, const short* __restrict__ kb,
    const short* __restrict__ vT,
    float* __restrict__ out, float* __restrict__ probs)
{
    __shared__ float pbuf[16][32][34];  // per-wave P transpose, 69.6 KB
    __shared__ float obuf[32][65];      // 8.3 KB
    __shared__ float sumbuf[32][17];    // 2.2 KB

    const int tid  = threadIdx.x;
    const int w    = tid >> 6;          // 0..15
    const int lane = tid & 63;
    const int l31  = lane & 31;
    const int h    = lane >> 5;

    const int b    = blockIdx.x & 7;
    const int row0 = (blockIdx.x >> 3) * 32;
    const int wk0  = w * 128;

    for (int i = tid; i < 32 * 65; i += 1024) ((float*)obuf)[i] = 0.f;

    // Q fragments (B operand of swapped QK^T)
    bf16x8 qf[4];
    const short* qrow = qb + ((long)(b * SS + row0 + l31)) * DD + h * 8;
    #pragma unroll
    for (int kt = 0; kt < 4; ++kt) qf[kt] = *(const bf16x8*)(qrow + kt * 16);

    // ---- pass A: QK^T chunks -> exp (no max) -> sum + bf16 pack ----
    unsigned P8[4][8];
    float s = 0.f;
    const short* kbase = kb + ((long)(b * SS + wk0 + l31)) * DD + h * 8;
    #pragma unroll
    for (int ct = 0; ct < 4; ++ct) {
        f32x16 a;
        #pragma unroll
        for (int i = 0; i < 16; ++i) a[i] = 0.f;
        const short* kp = kbase + (long)ct * 32 * DD;
        #pragma unroll
        for (int kt = 0; kt < 4; ++kt) {
            bf16x8 kf = *(const bf16x8*)(kp + kt * 16);
            a = __builtin_amdgcn_mfma_f32_32x32x16_bf16(kf, qf[kt], a, 0, 0, 0);
        }
        #pragma unroll
        for (int jj = 0; jj < 4; ++jj) {
            const float p0 = __builtin_amdgcn_exp2f(a[4 * jj + 0] * EXPC);
            const float p1 = __builtin_amdgcn_exp2f(a[4 * jj + 1] * EXPC);
            const float p2 = __builtin_amdgcn_exp2f(a[4 * jj + 2] * EXPC);
            const float p3 = __builtin_amdgcn_exp2f(a[4 * jj + 3] * EXPC);
            s += (p0 + p1) + (p2 + p3);
            unsigned u0, u1;
            asm("v_cvt_pk_bf16_f32 %0, %1, %2" : "=v"(u0) : "v"(p0), "v"(p1));
            asm("v_cvt_pk_bf16_f32 %0, %1, %2" : "=v"(u1) : "v"(p2), "v"(p3));
            P8[ct][2 * jj] = u0; P8[ct][2 * jj + 1] = u1;
        }
    }
    s += __shfl_xor(s, 32);
    if (lane < 32) sumbuf[l31][w] = s;
    __syncthreads();

    float gs = 0.f;
    #pragma unroll
    for (int i = 0; i < 16; ++i) gs += sumbuf[l31][i];
    const float inv = 1.f / gs;

    // ---- pass B: PV (V direct global) + probs store ----
    f32x16 oacc[2];
    #pragma unroll
    for (int i = 0; i < 16; ++i) { oacc[0][i] = 0.f; oacc[1][i] = 0.f; }

    const int qq  = lane >> 3, sg2 = lane & 7;    // probs store decomposition
    const short* vbase = vT + (long)b * DD * SS + wk0 + h * 8;

    #pragma unroll
    for (int ct = 0; ct < 4; ++ct) {
        // PV MFMA on unnormalized bf16 P, V from global (L2-resident)
        #pragma unroll
        for (int kk = 0; kk < 2; ++kk) {
            unsigned x0 = P8[ct][4 * kk + 0], x1 = P8[ct][4 * kk + 1];
            unsigned y0 = P8[ct][4 * kk + 2], y1 = P8[ct][4 * kk + 3];
            asm("v_permlane32_swap_b32 %0, %1" : "+v"(x0), "+v"(y0));
            asm("v_permlane32_swap_b32 %0, %1" : "+v"(x1), "+v"(y1));
            union { unsigned u[4]; bf16x8 v; } pf;
            pf.u[0] = x0; pf.u[1] = x1; pf.u[2] = y0; pf.u[3] = y1;
            #pragma unroll
            for (int nt = 0; nt < 2; ++nt) {
                bf16x8 vf = *(const bf16x8*)(vbase + (long)(nt * 32 + l31) * SS
                                             + ct * 32 + kk * 16);
                oacc[nt] = __builtin_amdgcn_mfma_f32_32x32x16_bf16(vf, pf.v, oacc[nt], 0, 0, 0);
            }
        }
        // probs: unpack, normalize, LDS transpose, coalesced NT store
        #pragma unroll
        for (int jj = 0; jj < 4; ++jj)
            #pragma unroll
            for (int u = 0; u < 2; ++u) {
                const unsigned pw = P8[ct][2 * jj + u];
                const float fa = __uint_as_float(pw << 16) * inv;
                const float fb = __uint_as_float(pw & 0xffff0000u) * inv;
                pbuf[w][l31][8 * jj + 4 * h + 2 * u + 0] = fa;
                pbuf[w][l31][8 * jj + 4 * h + 2 * u + 1] = fb;
            }
        #pragma unroll
        for (int jj = 0; jj < 4; ++jj) {
            const int q = qq + 8 * jj;
            float2 a2 = *(float2*)&pbuf[w][q][sg2 * 4];
            float2 b2 = *(float2*)&pbuf[w][q][sg2 * 4 + 2];
            f32x4 o4;
            o4[0] = a2.x; o4[1] = a2.y; o4[2] = b2.x; o4[3] = b2.y;
            __builtin_nontemporal_store(o4,
                (f32x4*)(probs + ((long)(b * SS + row0 + q)) * SS + wk0 + ct * 32 + sg2 * 4));
        }
    }

    // ---- cross-wave O reduce (oacc is O^T: row=d, col=q=l31) ----
    #pragma unroll
    for (int nt = 0; nt < 2; ++nt)
        #pragma unroll
        for (int i = 0; i < 16; ++i) {
            const int d = nt * 32 + (i & 3) + 8 * (i >> 2) + 4 * h;
            atomicAdd(&obuf[l31][d], oacc[nt][i] * inv);
        }
    __syncthreads();

    if (tid < 512) {
        const int q   = tid >> 4;
        const int seg = tid & 15;
        float4 val = make_float4(obuf[q][seg * 4 + 0], obuf[q][seg * 4 + 1],
                                 obuf[q][seg * 4 + 2], obuf[q][seg * 4 + 3]);
        *(float4*)(out + ((long)(b * SS + row0 + q)) * DD + seg * 4) = val;
    }
}

extern "C" void kernel_launch(void* const* d_in, const int* in_sizes, int n_in,
                              void* d_out, int out_size, void* d_ws, size_t ws_size,
                              hipStream_t stream) {
    const float* x  = (const float*)d_in[0];
    const float* Wq = (const float*)d_in[1];
    const float* bq = (const float*)d_in[2];
    const float* Wk = (const float*)d_in[3];
    const float* bk = (const float*)d_in[4];
    const float* Wv = (const float*)d_in[5];
    const float* bv = (const float*)d_in[6];

    float* out   = (float*)d_out;
    float* probs = (float*)d_out + (long)BB * SS * DD;

    short* q  = (short*)d_ws;                    // bf16 [B,S,D]
    short* k  = q + (long)BB * SS * DD;          // bf16 [B,S,D]
    short* vT = k + (long)BB * SS * DD;          // bf16 [B,D,S]
    short* wT = vT + (long)BB * SS * DD;         // bf16 [3][64][768]

    w_convert<<<36, 256, 0, stream>>>(Wq, Wk, Wv, wT);
    qkv_mfma<<<(BB * SS) / 32, 384, 0, stream>>>(x, wT, bq, bk, bv, q, k, vT);
    attn<<<BB * (SS / 32), 1024, 0, stream>>>(q, k, vT, out, probs);
}

// Round 10
// 134.748 us; speedup vs baseline: 1.1476x; 1.1476x over previous
//
#include <hip/hip_runtime.h>

#define BB 8
#define SS 2048
#define HH 768
#define DD 64
#define BK 64
#define NK (HH / BK)   // 12

typedef short bf16x8 __attribute__((ext_vector_type(8)));
typedef short bf16x4 __attribute__((ext_vector_type(4)));
typedef float f32x16 __attribute__((ext_vector_type(16)));
typedef float f32x4 __attribute__((ext_vector_type(4)));

#define EXPC 0.18033688011112042f   // log2(e)/8

static __device__ __forceinline__ short f2bf(float f) {
    union { float f; unsigned u; } v; v.f = f;
    unsigned u = v.u + 0x7fff + ((v.u >> 16) & 1);   // RNE
    return (short)(u >> 16);
}

// ---------------- Kernel 0: W transpose+convert -> wT bf16 [3][64][768] ----
__global__ __launch_bounds__(256) void w_convert(
    const float* __restrict__ Wq, const float* __restrict__ Wk,
    const float* __restrict__ Wv, short* __restrict__ wT)
{
    __shared__ float ws[64][65];
    const int jj   = blockIdx.x / 12;
    const int h0   = (blockIdx.x % 12) * 64;
    const int tid  = threadIdx.x;
    const float* Wsrc = (jj == 0) ? Wq : (jj == 1 ? Wk : Wv);

    {
        const int hl = tid >> 4;
        const int c4 = tid & 15;
        #pragma unroll
        for (int p = 0; p < 4; ++p) {
            const int h = hl + p * 16;
            float4 v = ((const float4*)(Wsrc + (long)(h0 + h) * DD))[c4];
            ws[h][c4 * 4 + 0] = v.x; ws[h][c4 * 4 + 1] = v.y;
            ws[h][c4 * 4 + 2] = v.z; ws[h][c4 * 4 + 3] = v.w;
        }
    }
    __syncthreads();

    const int d   = tid >> 2;
    const int seg = tid & 3;
    bf16x8 t0, t1;
    #pragma unroll
    for (int m = 0; m < 8; ++m) {
        t0[m] = f2bf(ws[seg * 16 + m][d]);
        t1[m] = f2bf(ws[seg * 16 + 8 + m][d]);
    }
    short* dst = wT + ((long)jj * 64 + d) * HH + h0 + seg * 16;
    *(bf16x8*)dst = t0;
    *(bf16x8*)(dst + 8) = t1;
}

// ---------------- Kernel 1: QKV projection via MFMA (unchanged) ----------
__global__ __launch_bounds__(384) void qkv_mfma(
    const float* __restrict__ x, const short* __restrict__ wT,
    const float* __restrict__ bq, const float* __restrict__ bk,
    const float* __restrict__ bv,
    short* __restrict__ qo, short* __restrict__ ko, short* __restrict__ vT)
{
    __shared__ short xs[2][32][68];

    const int tid  = threadIdx.x;
    const int w    = tid >> 6;
    const int lane = tid & 63;
    const int l31  = lane & 31;
    const int h    = lane >> 5;
    const long row0 = (long)blockIdx.x * 32;

    const int r0 = tid >> 4,        c0 = tid & 15;
    const int r1 = (tid + 384) >> 4, c1 = (tid + 384) & 15;
    const bool has1 = (tid + 384) < 512;

    f32x16 acc;
    #pragma unroll
    for (int i = 0; i < 16; ++i) acc[i] = 0.f;

    float4 st0, st1;
    st0 = ((const float4*)(x + (row0 + r0) * HH))[c0];
    if (has1) st1 = ((const float4*)(x + (row0 + r1) * HH))[c1];
    {
        bf16x4 b0; b0[0]=f2bf(st0.x); b0[1]=f2bf(st0.y); b0[2]=f2bf(st0.z); b0[3]=f2bf(st0.w);
        *(bf16x4*)&xs[0][r0][c0 * 4] = b0;
        if (has1) {
            bf16x4 b1; b1[0]=f2bf(st1.x); b1[1]=f2bf(st1.y); b1[2]=f2bf(st1.z); b1[3]=f2bf(st1.w);
            *(bf16x4*)&xs[0][r1][c1 * 4] = b1;
        }
    }
    __syncthreads();

    const int col = w * 32 + l31;
    const short* wcol = wT + (long)col * HH + h * 8;

    for (int it = 0; it < NK; ++it) {
        const int cur = it & 1;
        if (it < NK - 1) {
            st0 = ((const float4*)(x + (row0 + r0) * HH + (it + 1) * BK))[c0];
            if (has1) st1 = ((const float4*)(x + (row0 + r1) * HH + (it + 1) * BK))[c1];
        }
        #pragma unroll
        for (int kt = 0; kt < 4; ++kt) {
            bf16x8 af = *(const bf16x8*)&xs[cur][l31][kt * 16 + h * 8];
            bf16x8 bf = *(const bf16x8*)(wcol + it * BK + kt * 16);
            acc = __builtin_amdgcn_mfma_f32_32x32x16_bf16(af, bf, acc, 0, 0, 0);
        }
        if (it < NK - 1) {
            __syncthreads();
            bf16x4 b0; b0[0]=f2bf(st0.x); b0[1]=f2bf(st0.y); b0[2]=f2bf(st0.z); b0[3]=f2bf(st0.w);
            *(bf16x4*)&xs[cur ^ 1][r0][c0 * 4] = b0;
            if (has1) {
                bf16x4 b1; b1[0]=f2bf(st1.x); b1[1]=f2bf(st1.y); b1[2]=f2bf(st1.z); b1[3]=f2bf(st1.w);
                *(bf16x4*)&xs[cur ^ 1][r1][c1 * 4] = b1;
            }
            __syncthreads();
        }
    }

    short (*vs)[68] = xs[0];
    const int j = w >> 1;
    const int d = (w & 1) * 32 + l31;
    const float* bptr = (j == 0) ? bq : (j == 1 ? bk : bv);
    const float bias = bptr[d];

    __syncthreads();

    #pragma unroll
    for (int i = 0; i < 16; ++i) {
        const int r = (i & 3) + 8 * (i >> 2) + 4 * h;
        const short val = f2bf(acc[i] + bias);
        if (j == 0)      qo[(row0 + r) * DD + d] = val;
        else if (j == 1) ko[(row0 + r) * DD + d] = val;
        else             vs[r][d] = val;
    }
    __syncthreads();

    if (tid < 256) {
        const int b  = (int)(row0 >> 11);
        const int s0 = (int)(row0 & (SS - 1));
        const int dd  = tid >> 2;
        const int seg = tid & 3;
        bf16x8 t;
        #pragma unroll
        for (int m = 0; m < 8; ++m) t[m] = vs[seg * 8 + m][dd];
        *(bf16x8*)(vT + ((long)b * DD + dd) * SS + s0 + seg * 8) = t;
    }
}

// ---------------- Kernel 2: MFMA attention v6b (16x16, reg-local P) ------
// Identical to R9 except: NO min-waves launch_bounds (it forced VGPR<=64,
// heavy spills, and correlates with R6/R9 corruption).
__global__ __launch_bounds__(512) void attn(
    const short* __restrict__ qb, const short* __restrict__ kb,
    const short* __restrict__ vT,
    float* __restrict__ out, float* __restrict__ probs)
{
    __shared__ float obuf[16][65];     // 4.2 KB
    __shared__ float sumbuf[16][17];   // 1.1 KB

    const int tid  = threadIdx.x;
    const int w    = tid >> 6;
    const int lane = tid & 63;
    const int l15  = lane & 15;
    const int g    = (lane >> 4) & 3;

    const int b    = blockIdx.x & 7;           // XCD-pinned batch
    const int row0 = (blockIdx.x >> 3) * 16;
    const int wk0  = w * 256;

    for (int i = tid; i < 16 * 65; i += 512) ((float*)obuf)[i] = 0.f;

    // Q fragments (B operand of QK^T): q = l15, k(d) = g*8+e (+32)
    const short* qrow = qb + ((long)(b * SS + row0 + l15)) * DD + g * 8;
    const bf16x8 qf0 = *(const bf16x8*)(qrow);
    const bf16x8 qf1 = *(const bf16x8*)(qrow + 32);

    // ---- pass A: key-permuted QK^T -> exp -> pack ----
    // tile t of window wd loads K rows wd*32 + 4t + 8*(l15>>2) + (l15&3).
    // => lane (q=l15, g) reg r holds key wd*32 + 8g + 4t + r.
    unsigned P8[8][4];
    float s = 0.f;
    const int krow = 8 * (l15 >> 2) + (l15 & 3);
    const short* kbase = kb + ((long)(b * SS + wk0 + krow)) * DD + g * 8;
    #pragma unroll
    for (int wd = 0; wd < 8; ++wd) {
        #pragma unroll
        for (int t = 0; t < 2; ++t) {
            const short* kp = kbase + (long)(wd * 32 + 4 * t) * DD;
            f32x4 a = {0.f, 0.f, 0.f, 0.f};
            a = __builtin_amdgcn_mfma_f32_16x16x32_bf16(*(const bf16x8*)kp, qf0, a, 0, 0, 0);
            a = __builtin_amdgcn_mfma_f32_16x16x32_bf16(*(const bf16x8*)(kp + 32), qf1, a, 0, 0, 0);
            const float p0 = __builtin_amdgcn_exp2f(a[0] * EXPC);
            const float p1 = __builtin_amdgcn_exp2f(a[1] * EXPC);
            const float p2 = __builtin_amdgcn_exp2f(a[2] * EXPC);
            const float p3 = __builtin_amdgcn_exp2f(a[3] * EXPC);
            s += (p0 + p1) + (p2 + p3);
            unsigned u0, u1;
            asm("v_cvt_pk_bf16_f32 %0, %1, %2" : "=v"(u0) : "v"(p0), "v"(p1));
            asm("v_cvt_pk_bf16_f32 %0, %1, %2" : "=v"(u1) : "v"(p2), "v"(p3));
            P8[wd][2 * t] = u0; P8[wd][2 * t + 1] = u1;
        }
    }
    // reduce over the 4 lane groups sharing q = l15
    s += __shfl_xor(s, 16);
    s += __shfl_xor(s, 32);
    if (lane < 16) sumbuf[l15][w] = s;

    // ---- pass B: PV on unnormalized P ----
    f32x4 oacc[4];
    #pragma unroll
    for (int nt = 0; nt < 4; ++nt) { oacc[nt][0]=0.f; oacc[nt][1]=0.f; oacc[nt][2]=0.f; oacc[nt][3]=0.f; }

    const short* vbase = vT + (long)b * DD * SS + wk0 + g * 8;
    #pragma unroll
    for (int wd = 0; wd < 8; ++wd) {
        union { unsigned u[4]; bf16x8 v; } pf;
        pf.u[0] = P8[wd][0]; pf.u[1] = P8[wd][1];
        pf.u[2] = P8[wd][2]; pf.u[3] = P8[wd][3];
        #pragma unroll
        for (int nt = 0; nt < 4; ++nt) {
            const bf16x8 vf = *(const bf16x8*)(vbase + (long)(nt * 16 + l15) * SS + wd * 32);
            oacc[nt] = __builtin_amdgcn_mfma_f32_16x16x32_bf16(vf, pf.v, oacc[nt], 0, 0, 0);
        }
    }
    __syncthreads();

    float gs = 0.f;
    #pragma unroll
    for (int i = 0; i < 8; ++i) gs += sumbuf[l15][i];
    const float inv = 1.f / gs;

    // ---- probs: unpack x inv, contiguous 8-float register stores ----
    float* prow = probs + ((long)(b * SS + row0 + l15)) * SS + wk0 + 8 * g;
    #pragma unroll
    for (int wd = 0; wd < 8; ++wd) {
        f32x4 o0, o1;
        {
            const unsigned a0 = P8[wd][0], a1 = P8[wd][1];
            o0[0] = __uint_as_float(a0 << 16) * inv;
            o0[1] = __uint_as_float(a0 & 0xffff0000u) * inv;
            o0[2] = __uint_as_float(a1 << 16) * inv;
            o0[3] = __uint_as_float(a1 & 0xffff0000u) * inv;
        }
        {
            const unsigned a2 = P8[wd][2], a3 = P8[wd][3];
            o1[0] = __uint_as_float(a2 << 16) * inv;
            o1[1] = __uint_as_float(a2 & 0xffff0000u) * inv;
            o1[2] = __uint_as_float(a3 << 16) * inv;
            o1[3] = __uint_as_float(a3 & 0xffff0000u) * inv;
        }
        __builtin_nontemporal_store(o0, (f32x4*)(prow + wd * 32));
        __builtin_nontemporal_store(o1, (f32x4*)(prow + wd * 32 + 4));
    }

    // ---- cross-wave O reduce (oacc is O^T: d = nt*16+4g+r, q = l15) ----
    #pragma unroll
    for (int nt = 0; nt < 4; ++nt)
        #pragma unroll
        for (int r = 0; r < 4; ++r)
            atomicAdd(&obuf[l15][nt * 16 + 4 * g + r], oacc[nt][r] * inv);
    __syncthreads();

    if (tid < 256) {
        const int q  = tid >> 4;
        const int c4 = tid & 15;
        float4 val = make_float4(obuf[q][c4 * 4 + 0], obuf[q][c4 * 4 + 1],
                                 obuf[q][c4 * 4 + 2], obuf[q][c4 * 4 + 3]);
        *(float4*)(out + ((long)(b * SS + row0 + q)) * DD + c4 * 4) = val;
    }
}

extern "C" void kernel_launch(void* const* d_in, const int* in_sizes, int n_in,
                              void* d_out, int out_size, void* d_ws, size_t ws_size,
                              hipStream_t stream) {
    const float* x  = (const float*)d_in[0];
    const float* Wq = (const float*)d_in[1];
    const float* bq = (const float*)d_in[2];
    const float* Wk = (const float*)d_in[3];
    const float* bk = (const float*)d_in[4];
    const float* Wv = (const float*)d_in[5];
    const float* bv = (const float*)d_in[6];

    float* out   = (float*)d_out;
    float* probs = (float*)d_out + (long)BB * SS * DD;

    short* q  = (short*)d_ws;                    // bf16 [B,S,D]
    short* k  = q + (long)BB * SS * DD;          // bf16 [B,S,D]
    short* vT = k + (long)BB * SS * DD;          // bf16 [B,D,S]
    short* wT = vT + (long)BB * SS * DD;         // bf16 [3][64][768]

    w_convert<<<36, 256, 0, stream>>>(Wq, Wk, Wv, wT);
    qkv_mfma<<<(BB * SS) / 32, 384, 0, stream>>>(x, wT, bq, bk, bv, q, k, vT);
    attn<<<BB * (SS / 16), 512, 0, stream>>>(q, k, vT, out, probs);
}